// Round 5
// baseline (482.081 us; speedup 1.0000x reference)
//
#include <hip/hip_runtime.h>
#include <hip/hip_fp16.h>

// Shapes: feat0 [32,128,128,32], feat1 [32,128,32,128], feat2 [32,32,128,128]
// P = 524288 points per grid; out [3,32,P] fp32.
// All three feats transposed to [P][32] fp16 (96 MB total, MALL-resident).
// Identity term also read from the fp16 copy (coalesced) — keeps all sample
// traffic inside the MALL working set; only verts reads and output writes
// stream (non-temporal).

#define WS_P 524288
#define NCH 32

__device__ __forceinline__ float ntloadf(const float* p) {
    return __builtin_nontemporal_load(p);
}
__device__ __forceinline__ void ntstoref(float* p, float v) {
    __builtin_nontemporal_store(v, p);
}

// ---- ordered-uint encoding for float atomic min/max (exact, order-independent)
__device__ __forceinline__ unsigned encf(float f) {
    unsigned b = __float_as_uint(f);
    return (b & 0x80000000u) ? ~b : (b | 0x80000000u);
}
__device__ __forceinline__ float decf(unsigned u) {
    unsigned b = (u & 0x80000000u) ? (u & 0x7FFFFFFFu) : ~u;
    return __uint_as_float(b);
}

__global__ void init_mm_kernel(unsigned* mm) {
    int t = threadIdx.x;
    if (t < 18) mm[t] = (t & 1) ? 0u : 0xFFFFFFFFu;
}

__global__ __launch_bounds__(256) void minmax_kernel(
    const float* __restrict__ v0, const float* __restrict__ v1,
    const float* __restrict__ v2, unsigned* __restrict__ mm)
{
    const int g = blockIdx.y;
    const float* v = (g == 0) ? v0 : (g == 1) ? v1 : v2;
    const int tid = threadIdx.x;

    float mn[3] = { INFINITY, INFINITY, INFINITY };
    float mx[3] = { -INFINITY, -INFINITY, -INFINITY };

    for (int idx = blockIdx.x * 256 + tid; idx < WS_P; idx += 128 * 256) {
        #pragma unroll
        for (int k = 0; k < 3; k++) {
            float f = ntloadf(&v[(size_t)idx * 3 + k]);
            mn[k] = fminf(mn[k], f);
            mx[k] = fmaxf(mx[k], f);
        }
    }

    __shared__ float smn[3][256];
    __shared__ float smx[3][256];
    #pragma unroll
    for (int k = 0; k < 3; k++) { smn[k][tid] = mn[k]; smx[k][tid] = mx[k]; }
    __syncthreads();

    for (int s = 128; s > 0; s >>= 1) {
        if (tid < s) {
            #pragma unroll
            for (int k = 0; k < 3; k++) {
                smn[k][tid] = fminf(smn[k][tid], smn[k][tid + s]);
                smx[k][tid] = fmaxf(smx[k][tid], smx[k][tid + s]);
            }
        }
        __syncthreads();
    }

    if (tid == 0) {
        #pragma unroll
        for (int k = 0; k < 3; k++) {
            atomicMin(&mm[g * 6 + k * 2 + 0], encf(smn[k][0]));
            atomicMax(&mm[g * 6 + k * 2 + 1], encf(smx[k][0]));
        }
    }
}

// [C][N] fp32 -> [N][C] fp16 transpose, 32x32 tiles via LDS.
__global__ __launch_bounds__(256) void transpose16_kernel(
    const float* __restrict__ f0, const float* __restrict__ f1,
    const float* __restrict__ f2,
    __half* __restrict__ t0, __half* __restrict__ t1, __half* __restrict__ t2)
{
    const int j = blockIdx.y;
    const float* in = (j == 0) ? f0 : (j == 1) ? f1 : f2;
    __half* out = (j == 0) ? t0 : (j == 1) ? t1 : t2;

    __shared__ float tile[32][33];
    const int tx = threadIdx.x;   // 0..31
    const int ty = threadIdx.y;   // 0..7
    const int n0 = blockIdx.x * 32;

    #pragma unroll
    for (int r = 0; r < 4; r++) {
        int c = ty + r * 8;
        tile[c][tx] = ntloadf(&in[(size_t)c * WS_P + n0 + tx]);
    }
    __syncthreads();

    __half2* out2 = reinterpret_cast<__half2*>(out);
    const int tid = ty * 32 + tx;
    const int cp = tid & 15;           // channel pair 0..15
    #pragma unroll
    for (int r = 0; r < 2; r++) {
        int pl = (tid >> 4) + r * 16;  // point-in-tile 0..31
        float a = tile[cp * 2 + 0][pl];
        float b = tile[cp * 2 + 1][pl];
        out2[(size_t)(n0 + pl) * 16 + cp] = __floats2half2_rn(a, b);
    }
}

// 8 lanes per point; each lane owns 4 channels (8 B of the 64 B fp16 row).
template<int I>
__device__ __forceinline__ void sample_body(
    const __half* __restrict__ t0, const __half* __restrict__ t1,
    const __half* __restrict__ t2,
    const float* __restrict__ v0, const float* __restrict__ v1,
    const float* __restrict__ v2,
    const unsigned* __restrict__ mm, float* __restrict__ out,
    float (*sb)[33])
{
    constexpr int Dd[3] = { 128, 128, 32 };
    constexpr int Hh[3] = { 128, 32, 128 };
    constexpr int Ww[3] = { 32, 128, 128 };

    const int tid = threadIdx.x;
    const int p = blockIdx.x * 32 + (tid >> 3);   // point index
    const int subp = tid & 7;                     // which 4-channel group

    const float* verts = (I == 0) ? v0 : (I == 1) ? v1 : v2;
    const __half* ti   = (I == 0) ? t0 : (I == 1) ? t1 : t2;

    float g[3];
    #pragma unroll
    for (int k = 0; k < 3; k++) {
        float mn = decf(mm[I * 6 + k * 2 + 0]);
        float mx = decf(mm[I * 6 + k * 2 + 1]);
        float vv = ntloadf(&verts[(size_t)p * 3 + k]);
        g[k] = (vv - mn) / (mx - mn) * 2.0f - 1.0f;
    }

    // identity term from fp16 transposed copy (coalesced, MALL-resident)
    float4 acc;
    {
        uint2 rI = reinterpret_cast<const uint2*>(ti)[(size_t)p * 8 + subp];
        float2 i0 = __half22float2(*reinterpret_cast<__half2*>(&rI.x));
        float2 i1 = __half22float2(*reinterpret_cast<__half2*>(&rI.y));
        acc = make_float4(i0.x, i0.y, i1.x, i1.y);
    }

    #pragma unroll
    for (int jj = 0; jj < 2; jj++) {
        const int j = (I + 1 + jj) % 3;   // compile-time after unroll
        const __half* src = (j == 0) ? t0 : (j == 1) ? t1 : t2;
        const int W = Ww[j], H = Hh[j], D = Dd[j];

        float ix = (g[0] + 1.0f) * 0.5f * (float)(W - 1);
        float iy = (g[1] + 1.0f) * 0.5f * (float)(H - 1);
        float iz = (g[2] + 1.0f) * 0.5f * (float)(D - 1);
        float fx = floorf(ix), fy = floorf(iy), fz = floorf(iz);
        float wx = ix - fx, wy = iy - fy, wz = iz - fz;

        int x0 = (int)fx; x0 = x0 < 0 ? 0 : (x0 > W - 1 ? W - 1 : x0);
        int y0 = (int)fy; y0 = y0 < 0 ? 0 : (y0 > H - 1 ? H - 1 : y0);
        int z0 = (int)fz; z0 = z0 < 0 ? 0 : (z0 > D - 1 ? D - 1 : z0);
        int x1 = (x0 + 1 > W - 1) ? W - 1 : x0 + 1;
        int y1 = (y0 + 1 > H - 1) ? H - 1 : y0 + 1;
        int z1 = (z0 + 1 > D - 1) ? D - 1 : z0 + 1;

        float ux = 1.0f - wx, uy = 1.0f - wy, uz = 1.0f - wz;
        float w[8] = { uz * uy * ux, uz * uy * wx, uz * wy * ux, uz * wy * wx,
                       wz * uy * ux, wz * uy * wx, wz * wy * ux, wz * wy * wx };

        int r00 = (z0 * H + y0) * W;
        int r01 = (z0 * H + y1) * W;
        int r10 = (z1 * H + y0) * W;
        int r11 = (z1 * H + y1) * W;
        int o[8] = { r00 + x0, r00 + x1, r01 + x0, r01 + x1,
                     r10 + x0, r10 + x1, r11 + x0, r11 + x1 };

        const uint2* s8 = reinterpret_cast<const uint2*>(src);
        #pragma unroll
        for (int h = 0; h < 2; h++) {
            uint2 rA = s8[(size_t)o[h * 4 + 0] * 8 + subp];
            uint2 rB = s8[(size_t)o[h * 4 + 1] * 8 + subp];
            uint2 rC = s8[(size_t)o[h * 4 + 2] * 8 + subp];
            uint2 rD = s8[(size_t)o[h * 4 + 3] * 8 + subp];
            float wA = w[h * 4 + 0], wB = w[h * 4 + 1];
            float wC = w[h * 4 + 2], wD = w[h * 4 + 3];
            float2 a0 = __half22float2(*reinterpret_cast<__half2*>(&rA.x));
            float2 a1 = __half22float2(*reinterpret_cast<__half2*>(&rA.y));
            float2 b0 = __half22float2(*reinterpret_cast<__half2*>(&rB.x));
            float2 b1 = __half22float2(*reinterpret_cast<__half2*>(&rB.y));
            float2 c0 = __half22float2(*reinterpret_cast<__half2*>(&rC.x));
            float2 c1 = __half22float2(*reinterpret_cast<__half2*>(&rC.y));
            float2 d0 = __half22float2(*reinterpret_cast<__half2*>(&rD.x));
            float2 d1 = __half22float2(*reinterpret_cast<__half2*>(&rD.y));
            acc.x = fmaf(wA, a0.x, acc.x); acc.y = fmaf(wA, a0.y, acc.y);
            acc.z = fmaf(wA, a1.x, acc.z); acc.w = fmaf(wA, a1.y, acc.w);
            acc.x = fmaf(wB, b0.x, acc.x); acc.y = fmaf(wB, b0.y, acc.y);
            acc.z = fmaf(wB, b1.x, acc.z); acc.w = fmaf(wB, b1.y, acc.w);
            acc.x = fmaf(wC, c0.x, acc.x); acc.y = fmaf(wC, c0.y, acc.y);
            acc.z = fmaf(wC, c1.x, acc.z); acc.w = fmaf(wC, c1.y, acc.w);
            acc.x = fmaf(wD, d0.x, acc.x); acc.y = fmaf(wD, d0.y, acc.y);
            acc.z = fmaf(wD, d1.x, acc.z); acc.w = fmaf(wD, d1.y, acc.w);
        }
    }

    // transpose through LDS; NT store straight out (identity already in acc)
    const int pl = tid >> 3;
    sb[pl][subp * 4 + 0] = acc.x;
    sb[pl][subp * 4 + 1] = acc.y;
    sb[pl][subp * 4 + 2] = acc.z;
    sb[pl][subp * 4 + 3] = acc.w;
    __syncthreads();

    const int p0 = blockIdx.x * 32;
    float* op = out + (size_t)I * NCH * WS_P;
    #pragma unroll
    for (int it = 0; it < 4; it++) {
        int c = it * 8 + (tid >> 5);
        size_t off = (size_t)c * WS_P + p0 + (tid & 31);
        ntstoref(&op[off], sb[tid & 31][c]);
    }
}

__global__ __launch_bounds__(256, 8) void fused_sample_kernel(
    const __half* __restrict__ t0, const __half* __restrict__ t1,
    const __half* __restrict__ t2,
    const float* __restrict__ v0, const float* __restrict__ v1,
    const float* __restrict__ v2,
    const unsigned* __restrict__ mm, float* __restrict__ out)
{
    __shared__ float sb[32][33];
    switch (blockIdx.y) {
        case 0: sample_body<0>(t0, t1, t2, v0, v1, v2, mm, out, sb); break;
        case 1: sample_body<1>(t0, t1, t2, v0, v1, v2, mm, out, sb); break;
        default: sample_body<2>(t0, t1, t2, v0, v1, v2, mm, out, sb); break;
    }
}

// fallback (ws too small): 1-thread-per-point scalar-gather from original layout
template<int I>
__global__ __launch_bounds__(256) void sample_fallback_kernel(
    const float* __restrict__ f0, const float* __restrict__ f1,
    const float* __restrict__ f2,
    const float* __restrict__ v0, const float* __restrict__ v1,
    const float* __restrict__ v2,
    const unsigned* __restrict__ mm, float* __restrict__ out)
{
    constexpr int Dd[3] = { 128, 128, 32 };
    constexpr int Hh[3] = { 128, 32, 128 };
    constexpr int Ww[3] = { 32, 128, 128 };

    const int p = blockIdx.x * 256 + threadIdx.x;
    const float* verts = (I == 0) ? v0 : (I == 1) ? v1 : v2;
    const float* fi    = (I == 0) ? f0 : (I == 1) ? f1 : f2;

    float g[3];
    #pragma unroll
    for (int k = 0; k < 3; k++) {
        float mn = decf(mm[I * 6 + k * 2 + 0]);
        float mx = decf(mm[I * 6 + k * 2 + 1]);
        float vv = verts[(size_t)p * 3 + k];
        g[k] = (vv - mn) / (mx - mn) * 2.0f - 1.0f;
    }

    float acc[NCH];
    #pragma unroll
    for (int c = 0; c < NCH; c++) acc[c] = fi[(size_t)c * WS_P + p];

    #pragma unroll
    for (int jj = 0; jj < 2; jj++) {
        const int j = (I + 1 + jj) % 3;
        const float* src = (j == 0) ? f0 : (j == 1) ? f1 : f2;
        const int W = Ww[j], H = Hh[j], D = Dd[j];

        float ix = (g[0] + 1.0f) * 0.5f * (float)(W - 1);
        float iy = (g[1] + 1.0f) * 0.5f * (float)(H - 1);
        float iz = (g[2] + 1.0f) * 0.5f * (float)(D - 1);
        float fx = floorf(ix), fy = floorf(iy), fz = floorf(iz);
        float wx = ix - fx, wy = iy - fy, wz = iz - fz;

        int x0 = (int)fx; x0 = x0 < 0 ? 0 : (x0 > W - 1 ? W - 1 : x0);
        int y0 = (int)fy; y0 = y0 < 0 ? 0 : (y0 > H - 1 ? H - 1 : y0);
        int z0 = (int)fz; z0 = z0 < 0 ? 0 : (z0 > D - 1 ? D - 1 : z0);
        int x1 = (x0 + 1 > W - 1) ? W - 1 : x0 + 1;
        int y1 = (y0 + 1 > H - 1) ? H - 1 : y0 + 1;
        int z1 = (z0 + 1 > D - 1) ? D - 1 : z0 + 1;

        float ux = 1.0f - wx, uy = 1.0f - wy, uz = 1.0f - wz;
        float w[8] = { uz * uy * ux, uz * uy * wx, uz * wy * ux, uz * wy * wx,
                       wz * uy * ux, wz * uy * wx, wz * wy * ux, wz * wy * wx };

        int r00 = (z0 * H + y0) * W;
        int r01 = (z0 * H + y1) * W;
        int r10 = (z1 * H + y0) * W;
        int r11 = (z1 * H + y1) * W;
        int o[8] = { r00 + x0, r00 + x1, r01 + x0, r01 + x1,
                     r10 + x0, r10 + x1, r11 + x0, r11 + x1 };

        #pragma unroll
        for (int cn = 0; cn < 8; cn++) {
            float wt = w[cn];
            const float* sp = src + o[cn];
            #pragma unroll
            for (int c = 0; c < NCH; c++)
                acc[c] = fmaf(wt, sp[(size_t)c * WS_P], acc[c]);
        }
    }

    float* op = out + (size_t)I * NCH * WS_P + p;
    #pragma unroll
    for (int c = 0; c < NCH; c++) op[(size_t)c * WS_P] = acc[c];
}

extern "C" void kernel_launch(void* const* d_in, const int* in_sizes, int n_in,
                              void* d_out, int out_size, void* d_ws, size_t ws_size,
                              hipStream_t stream) {
    const float* f0 = (const float*)d_in[0];
    const float* f1 = (const float*)d_in[1];
    const float* f2 = (const float*)d_in[2];
    const float* v0 = (const float*)d_in[3];
    const float* v1 = (const float*)d_in[4];
    const float* v2 = (const float*)d_in[5];
    float* out = (float*)d_out;

    unsigned* mm = (unsigned*)d_ws;
    const size_t FEAT_ELEMS = (size_t)NCH * WS_P;
    __half* t0 = (__half*)((char*)d_ws + 256);
    __half* t1 = t0 + FEAT_ELEMS;
    __half* t2 = t1 + FEAT_ELEMS;
    const bool tr = ws_size >= 256 + 3 * FEAT_ELEMS * sizeof(__half);

    hipLaunchKernelGGL(init_mm_kernel, dim3(1), dim3(32), 0, stream, mm);
    hipLaunchKernelGGL(minmax_kernel, dim3(128, 3), dim3(256), 0, stream,
                       v0, v1, v2, mm);

    if (tr) {
        hipLaunchKernelGGL(transpose16_kernel, dim3(WS_P / 32, 3), dim3(32, 8), 0,
                           stream, f0, f1, f2, t0, t1, t2);
        hipLaunchKernelGGL(fused_sample_kernel, dim3(WS_P / 32, 3), dim3(256), 0,
                           stream, t0, t1, t2, v0, v1, v2, mm, out);
    } else {
        hipLaunchKernelGGL((sample_fallback_kernel<0>), dim3(WS_P / 256), dim3(256), 0,
                           stream, f0, f1, f2, v0, v1, v2, mm, out);
        hipLaunchKernelGGL((sample_fallback_kernel<1>), dim3(WS_P / 256), dim3(256), 0,
                           stream, f0, f1, f2, v0, v1, v2, mm, out);
        hipLaunchKernelGGL((sample_fallback_kernel<2>), dim3(WS_P / 256), dim3(256), 0,
                           stream, f0, f1, f2, v0, v1, v2, mm, out);
    }
}